// Round 11
// baseline (111.244 us; speedup 1.0000x reference)
//
#include <hip/hip_runtime.h>

// KDA delta-rule state update, B=H=32, K=V=256, fp32.
// out[k,v] = g[k]*S[k,v] + cb[k]*(val[v] - kt[v]),
//   w[k] = g[k]*key[k], cb[k] = beta*key[k], kt[v] = sum_k w[k]*S[k,v].
//
// R11 = R10's wave-autonomous structure (lane (r8,c8) owns 32 rows x one
// f32x4 col; 128B chunks; in-wave butterfly kt; no barriers in main body)
// made PERSISTENT: grid = 512 = exactly 2 blocks/CU, each block runs 4
// half-tiles back-to-back. Register recycling lets tile n's store burst
// overlap tile n+1's load burst (load s[j] depends only on the VALU
// compute that consumed s[j], not on store completion).

#define KD 256
#define VD 256
#define VD4 (VD / 4)   // 64 f32x4 per row
#define TILES_PER_BLOCK 4

typedef float f32x4 __attribute__((ext_vector_type(4)));

__global__ __launch_bounds__(256, 2)
void kda_update_kernel(const float* __restrict__ state,
                       const float* __restrict__ keys,
                       const float* __restrict__ values,
                       const float* __restrict__ gates,
                       const float* __restrict__ beta,
                       float* __restrict__ out)
{
    const int blk = blockIdx.x;          // 0..511
    const int bh0 = 2 * blk;             // this block's two (b,h) tiles

    __shared__ float s_g[2][KD];   // alpha
    __shared__ float s_w[2][KD];   // alpha*key
    __shared__ float s_c[2][KD];   // beta*key

    const int t    = threadIdx.x;
    const int wv   = t >> 6;             // wave 0..3
    const int lane = t & 63;
    const int r8   = lane >> 3;          // row residue 0..7
    const int c8   = lane & 7;           // f32x4 col within wave's 8

    // ---- stage scalars for BOTH bh once (the only barrier) ----
#pragma unroll
    for (int i = 0; i < 2; ++i) {
        const int bh = bh0 + i;
        const float g = gates[bh * KD + t];
        const float k = keys[bh * KD + t];
        s_g[i][t] = g;
        s_w[i][t] = g * k;
        s_c[i][t] = beta[bh] * k;
    }
    __syncthreads();

    // ---- 4 half-tiles, barrier-free, registers recycled across tiles ----
#pragma unroll 1
    for (int it = 0; it < TILES_PER_BLOCK; ++it) {
        const int i    = it >> 1;                    // local bh index 0/1
        const int half = it & 1;                     // V half
        const int bh   = bh0 + i;
        const size_t toff = (size_t)bh * (KD * VD);
        const f32x4* __restrict__ S4 = (const f32x4*)(state + toff);
        f32x4* __restrict__ O4 = (f32x4*)(out + toff);

        const int col = half * 32 + wv * 8 + c8;     // lane's f32x4 column

        // load all 256 rows of this lane's column (32 f32x4, 128B chunks)
        f32x4 s[32];
#pragma unroll
        for (int j = 0; j < 32; ++j)
            s[j] = __builtin_nontemporal_load(&S4[(size_t)(r8 + 8 * j) * VD4 + col]);

        // in-lane kt partial over this lane's 32 rows
        f32x4 p = (f32x4)(0.f);
#pragma unroll
        for (int j = 0; j < 32; ++j) {
            const float w = s_w[i][r8 + 8 * j];      // broadcast over c8
            p.x = fmaf(w, s[j].x, p.x);
            p.y = fmaf(w, s[j].y, p.y);
            p.z = fmaf(w, s[j].z, p.z);
            p.w = fmaf(w, s[j].w, p.w);
        }

        // in-wave reduce over r8 (lane bits 3..5)
#pragma unroll
        for (int m = 8; m <= 32; m <<= 1) {
            p.x += __shfl_xor(p.x, m, 64);
            p.y += __shfl_xor(p.y, m, 64);
            p.z += __shfl_xor(p.z, m, 64);
            p.w += __shfl_xor(p.w, m, 64);
        }

        const f32x4 vv = ((const f32x4*)(values + (size_t)bh * VD))[col];
        f32x4 d;
        d.x = vv.x - p.x; d.y = vv.y - p.y;
        d.z = vv.z - p.z; d.w = vv.w - p.w;

        // output: s[j] dead right after its o is computed -> next tile's
        // load into s[j] can issue while these stores are still in flight
#pragma unroll
        for (int j = 0; j < 32; ++j) {
            const int r = r8 + 8 * j;
            const float g  = s_g[i][r];
            const float cb = s_c[i][r];
            f32x4 o;
            o.x = fmaf(g, s[j].x, cb * d.x);
            o.y = fmaf(g, s[j].y, cb * d.y);
            o.z = fmaf(g, s[j].z, cb * d.z);
            o.w = fmaf(g, s[j].w, cb * d.w);
            __builtin_nontemporal_store(o, &O4[(size_t)r * VD4 + col]);
        }
    }
}

extern "C" void kernel_launch(void* const* d_in, const int* in_sizes, int n_in,
                              void* d_out, int out_size, void* d_ws, size_t ws_size,
                              hipStream_t stream) {
    const float* state  = (const float*)d_in[0];
    const float* keys   = (const float*)d_in[1];
    const float* values = (const float*)d_in[2];
    const float* gates  = (const float*)d_in[3];
    const float* beta   = (const float*)d_in[4];
    float* out = (float*)d_out;

    dim3 grid(512);    // 2 blocks/CU exactly; 4 half-tiles per block
    dim3 block(256);
    hipLaunchKernelGGL(kda_update_kernel, grid, block, 0, stream,
                       state, keys, values, gates, beta, out);
}